// Round 2
// baseline (532.925 us; speedup 1.0000x reference)
//
#include <hip/hip_runtime.h>

#define BB 64
#define TO 36
#define TW 32
#define DD 512

typedef short short8 __attribute__((ext_vector_type(8)));
typedef float floatx4 __attribute__((ext_vector_type(4)));

// ---- helpers -------------------------------------------------------------

__device__ __forceinline__ unsigned short f2bf(float f) {
  unsigned int x = __builtin_bit_cast(unsigned int, f);
  x += 0x7FFFu + ((x >> 16) & 1u);
  return (unsigned short)(x >> 16);
}

__device__ __forceinline__ short8 ld8(const unsigned short* p) {
  return __builtin_bit_cast(short8, *(const uint4*)p);
}

// ---- prep: f32->bf16 conversions + o transpose ---------------------------
// blocks 0..511    : w  (64*32*512 floats, 8/thread)
// blocks 512..1087 : u  (64*36*512 floats, 8/thread)
// blocks 1088..1215: ot[b][d][64] bf16, o-index padded 36->64 with zeros
__global__ __launch_bounds__(256) void prep_kernel(
    const float* __restrict__ o_g, const float* __restrict__ u_g,
    const float* __restrict__ w_g, unsigned short* __restrict__ wbf,
    unsigned short* __restrict__ ubf, unsigned short* __restrict__ ot) {
  const int blk = blockIdx.x, tid = threadIdx.x;
  if (blk < 512) {
    int i8 = blk * 256 + tid;
    const float4* src = (const float4*)w_g;
    float4 f0 = src[i8 * 2], f1 = src[i8 * 2 + 1];
    uint4 d;
    d.x = (unsigned)f2bf(f0.x) | ((unsigned)f2bf(f0.y) << 16);
    d.y = (unsigned)f2bf(f0.z) | ((unsigned)f2bf(f0.w) << 16);
    d.z = (unsigned)f2bf(f1.x) | ((unsigned)f2bf(f1.y) << 16);
    d.w = (unsigned)f2bf(f1.z) | ((unsigned)f2bf(f1.w) << 16);
    ((uint4*)wbf)[i8] = d;
  } else if (blk < 1088) {
    int i8 = (blk - 512) * 256 + tid;
    const float4* src = (const float4*)u_g;
    float4 f0 = src[i8 * 2], f1 = src[i8 * 2 + 1];
    uint4 d;
    d.x = (unsigned)f2bf(f0.x) | ((unsigned)f2bf(f0.y) << 16);
    d.y = (unsigned)f2bf(f0.z) | ((unsigned)f2bf(f0.w) << 16);
    d.z = (unsigned)f2bf(f1.x) | ((unsigned)f2bf(f1.y) << 16);
    d.w = (unsigned)f2bf(f1.z) | ((unsigned)f2bf(f1.w) << 16);
    ((uint4*)ubf)[i8] = d;
  } else {
    // coalesced: at fixed o, the 512 threads of 2 blocks cover consecutive d
    int t2 = (blk - 1088) * 256 + tid;  // (b, d)
    int b = t2 >> 9, d = t2 & 511;
    uint4 bufv[8];
    unsigned short* buf = (unsigned short*)bufv;
#pragma unroll
    for (int o = 0; o < 64; ++o)
      buf[o] = (o < TO) ? f2bf(o_g[((b * TO + o) << 9) + d]) : (unsigned short)0;
    uint4* dst = (uint4*)(ot + ((size_t)((b << 9) + d) << 6));
#pragma unroll
    for (int i = 0; i < 8; ++i) dst[i] = bufv[i];
  }
}

// ---- main: per-(wb,b), 2 waves t-split; fused GEMM1->softmax->GEMM2 ------
__global__ __launch_bounds__(128) void main_kernel(
    const float* __restrict__ w_g,
    const unsigned short* __restrict__ wbf,
    const unsigned short* __restrict__ ubf,
    const unsigned short* __restrict__ ot,
    float* __restrict__ logits_ws,
    float* __restrict__ att_out,
    float* __restrict__ attV_out) {
  const int b = blockIdx.x, wb = blockIdx.y;
  const int tid = threadIdx.x;
  const int wave = tid >> 6;   // t-half: rows [wave*16, wave*16+16)
  const int lane = tid & 63;
  const int c = lane & 15;     // col within 16x16 tile
  const int q = lane >> 4;     // quad 0..3

  __shared__ unsigned short att_s[2][16][72];  // per-wave bf16 att, K-pad 64
  {
    unsigned int* p = (unsigned int*)&att_s[wave][0][0];  // 576 dwords/wave
#pragma unroll
    for (int i = 0; i < 9; ++i) p[lane + 64 * i] = 0u;
  }

  // ---------------- GEMM1: scores[t][o], t in this wave's half -----------
  const unsigned short* wbp = wbf + (size_t)wb * TW * DD + (size_t)wave * 16 * DD;
  const unsigned short* ubp = ubf + (size_t)b * TO * DD;

  floatx4 acc[3];
#pragma unroll
  for (int j = 0; j < 3; ++j) acc[j] = (floatx4){0.f, 0.f, 0.f, 0.f};

  int r2 = 32 + c; if (r2 > 35) r2 = 35;  // clamp; cols 36..47 discarded
#pragma unroll 2
  for (int kk = 0; kk < 16; ++kk) {
    int k0 = kk * 32 + q * 8;
    short8 a0 = ld8(wbp + c * DD + k0);
    short8 u0 = ld8(ubp + c * DD + k0);
    short8 u1 = ld8(ubp + (16 + c) * DD + k0);
    short8 u2 = ld8(ubp + r2 * DD + k0);
    acc[0] = __builtin_amdgcn_mfma_f32_16x16x32_bf16(a0, u0, acc[0], 0, 0, 0);
    acc[1] = __builtin_amdgcn_mfma_f32_16x16x32_bf16(a0, u1, acc[1], 0, 0, 0);
    acc[2] = __builtin_amdgcn_mfma_f32_16x16x32_bf16(a0, u2, acc[2], 0, 0, 0);
  }

  // ------------- softmax over o (row lives in one quad's 16 lanes) -------
  const float scale = 0.04419417382415922f;  // 1/sqrt(512)
  const bool v2 = (c < 4);                   // col 32+c valid iff < 36
  float* attb = att_out + (size_t)(wb * BB + b) * TW * TO;
#pragma unroll
  for (int reg = 0; reg < 4; ++reg) {
    float s0 = acc[0][reg] * scale;
    float s1 = acc[1][reg] * scale;
    float s2 = acc[2][reg] * scale;
    float m = fmaxf(s0, s1);
    if (v2) m = fmaxf(m, s2);
#pragma unroll
    for (int off = 1; off < 16; off <<= 1) m = fmaxf(m, __shfl_xor(m, off));
    float e0 = __expf(s0 - m);
    float e1 = __expf(s1 - m);
    float e2 = v2 ? __expf(s2 - m) : 0.f;
    float sum = e0 + e1 + e2;
#pragma unroll
    for (int off = 1; off < 16; off <<= 1) sum += __shfl_xor(sum, off);
    float inv = 1.f / sum;
    float a0v = e0 * inv, a1v = e1 * inv, a2v = e2 * inv;
    int t = wave * 16 + q * 4 + reg;
    __builtin_nontemporal_store(a0v, &attb[t * TO + c]);
    __builtin_nontemporal_store(a1v, &attb[t * TO + 16 + c]);
    if (v2) __builtin_nontemporal_store(a2v, &attb[t * TO + 32 + c]);
    att_s[wave][q * 4 + reg][c] = f2bf(a0v);
    att_s[wave][q * 4 + reg][16 + c] = f2bf(a1v);
    if (v2) att_s[wave][q * 4 + reg][32 + c] = f2bf(a2v);
  }
  __syncthreads();  // order LDS writes before cross-lane reads (cheap: 2 waves)

  // ------------- GEMM2: att_V_o[t][d] = sum_o att[t][o]*o[o][d] ----------
  short8 a2f[2];
  a2f[0] = ld8(&att_s[wave][c][q * 8]);
  a2f[1] = ld8(&att_s[wave][c][32 + q * 8]);

  const unsigned short* otp = ot + (size_t)b * DD * 64;
  const float* wrow = w_g + (size_t)wb * TW * DD + (size_t)wave * 16 * DD;
  float* avb = attV_out + (size_t)(wb * BB + b) * TW * DD + (size_t)wave * 16 * DD;
  float lp[4] = {0.f, 0.f, 0.f, 0.f};

#pragma unroll 4
  for (int nt2 = 0; nt2 < 32; ++nt2) {
    int d0 = nt2 * 16;
    short8 b0 = ld8(otp + (d0 + c) * 64 + q * 8);
    short8 b1 = ld8(otp + (d0 + c) * 64 + 32 + q * 8);
    floatx4 a = (floatx4){0.f, 0.f, 0.f, 0.f};
    a = __builtin_amdgcn_mfma_f32_16x16x32_bf16(a2f[0], b0, a, 0, 0, 0);
    a = __builtin_amdgcn_mfma_f32_16x16x32_bf16(a2f[1], b1, a, 0, 0, 0);
#pragma unroll
    for (int reg = 0; reg < 4; ++reg) {
      int t = q * 4 + reg;  // within this wave's 16 rows
      float v = a[reg];
      __builtin_nontemporal_store(v, &avb[t * DD + d0 + c]);
      lp[reg] = fmaf(v, wrow[t * DD + d0 + c], lp[reg]);
    }
  }

  // logits[t] = quad-column sum of lane partials
#pragma unroll
  for (int reg = 0; reg < 4; ++reg) {
    float s = lp[reg];
#pragma unroll
    for (int off = 1; off < 16; off <<= 1) s += __shfl_xor(s, off);
    if (c == 0) {
      int t = wave * 16 + q * 4 + reg;
      logits_ws[(size_t)(wb * BB + b) * TW + t] = s;
    }
  }
}

// ---- loss: log_softmax over Bo + masked mean -----------------------------
__global__ __launch_bounds__(64) void loss_kernel(
    const float* __restrict__ logits, const int* __restrict__ mask,
    float* __restrict__ out) {
  int wb = blockIdx.x, lane = threadIdx.x;  // lane = b
  const float* lrow = logits + ((size_t)wb * BB + lane) * TW;
  float accv = 0.f, nnm = 0.f;
  for (int t = 0; t < TW; ++t) {
    float v = lrow[t];
    float m = v;
#pragma unroll
    for (int off = 1; off < 64; off <<= 1) m = fmaxf(m, __shfl_xor(m, off));
    float e = __expf(v - m);
    float s = e;
#pragma unroll
    for (int off = 1; off < 64; off <<= 1) s += __shfl_xor(s, off);
    float diag = __shfl(v, wb);  // logits[wb][wb][t]
    float lsm = diag - m - __logf(s);
    float keep = 1.f - (float)mask[wb * TW + t];
    accv += lsm * keep;
    nnm += keep;
  }
  if (lane == 0) atomicAdd(out, -(accv / (nnm + 1e-6f)) * (1.f / 64.f));
}

// ---- launch --------------------------------------------------------------
extern "C" void kernel_launch(void* const* d_in, const int* in_sizes, int n_in,
                              void* d_out, int out_size, void* d_ws, size_t ws_size,
                              hipStream_t stream) {
  const float* o_g = (const float*)d_in[0];   // (64,36,512) f32
  const float* u_g = (const float*)d_in[1];   // (64,36,512) f32
  const float* w_g = (const float*)d_in[2];   // (64,32,512) f32
  const int* mask  = (const int*)d_in[3];     // (64,32) i32

  float* out = (float*)d_out;
  float* att_out  = out + 1;
  float* attV_out = out + 1 + (size_t)BB * BB * TW * TO;

  char* ws = (char*)d_ws;
  unsigned short* wbf = (unsigned short*)(ws + 0);         // 2,097,152 B
  unsigned short* ubf = (unsigned short*)(ws + 2097152);   // 2,359,296 B
  unsigned short* ot  = (unsigned short*)(ws + 4456448);   // 4,194,304 B
  float* logits       = (float*)(ws + 8650752);            //   524,288 B

  hipMemsetAsync(d_out, 0, sizeof(float), stream);  // loss accumulator
  prep_kernel<<<1216, 256, 0, stream>>>(o_g, u_g, w_g, wbf, ubf, ot);
  main_kernel<<<dim3(BB, BB), 128, 0, stream>>>(w_g, wbf, ubf, ot, logits,
                                                att_out, attV_out);
  loss_kernel<<<BB, 64, 0, stream>>>(logits, mask, out);
}

// Round 3
// 480.564 us; speedup vs baseline: 1.1090x; 1.1090x over previous
//
#include <hip/hip_runtime.h>

#define BB 64
#define TO 36
#define TW 32
#define DD 512

typedef short short8 __attribute__((ext_vector_type(8)));
typedef float floatx4 __attribute__((ext_vector_type(4)));
typedef float floatx16 __attribute__((ext_vector_type(16)));

// ---- helpers -------------------------------------------------------------

__device__ __forceinline__ unsigned short f2bf(float f) {
  unsigned int x = __builtin_bit_cast(unsigned int, f);
  x += 0x7FFFu + ((x >> 16) & 1u);
  return (unsigned short)(x >> 16);
}

__device__ __forceinline__ short8 ld8(const unsigned short* p) {
  return __builtin_bit_cast(short8, *(const uint4*)p);
}

__device__ __forceinline__ uint4 cvt8(const float4 f0, const float4 f1) {
  uint4 d;
  d.x = (unsigned)f2bf(f0.x) | ((unsigned)f2bf(f0.y) << 16);
  d.y = (unsigned)f2bf(f0.z) | ((unsigned)f2bf(f0.w) << 16);
  d.z = (unsigned)f2bf(f1.x) | ((unsigned)f2bf(f1.y) << 16);
  d.w = (unsigned)f2bf(f1.z) | ((unsigned)f2bf(f1.w) << 16);
  return d;
}

// ---- prep: f32->bf16 conversions + o transpose ---------------------------
// blocks 0..511    : w->wbf     (1,048,576 floats, 8/thread)
// blocks 512..1087 : u->ubf     (1,179,648 floats)
// blocks 1088..1663: o->obf     (1,179,648 floats, row-major bf16)
// blocks 1664..1791: o->ot[b][d][o64] bf16, o padded 36->64 with zeros
__global__ __launch_bounds__(256) void prep_kernel(
    const float* __restrict__ o_g, const float* __restrict__ u_g,
    const float* __restrict__ w_g, unsigned short* __restrict__ wbf,
    unsigned short* __restrict__ ubf, unsigned short* __restrict__ obf,
    unsigned short* __restrict__ ot) {
  const int blk = blockIdx.x, tid = threadIdx.x;
  if (blk < 512) {
    int i8 = blk * 256 + tid;
    const float4* src = (const float4*)w_g;
    ((uint4*)wbf)[i8] = cvt8(src[i8 * 2], src[i8 * 2 + 1]);
  } else if (blk < 1088) {
    int i8 = (blk - 512) * 256 + tid;
    const float4* src = (const float4*)u_g;
    ((uint4*)ubf)[i8] = cvt8(src[i8 * 2], src[i8 * 2 + 1]);
  } else if (blk < 1664) {
    int i8 = (blk - 1088) * 256 + tid;
    const float4* src = (const float4*)o_g;
    ((uint4*)obf)[i8] = cvt8(src[i8 * 2], src[i8 * 2 + 1]);
  } else {
    int t2 = (blk - 1664) * 256 + tid;  // (b, d)
    int b = t2 >> 9, d = t2 & 511;
    uint4 bufv[8];
    unsigned short* buf = (unsigned short*)bufv;
#pragma unroll
    for (int o = 0; o < 64; ++o)
      buf[o] = (o < TO) ? f2bf(o_g[((b * TO + o) << 9) + d]) : (unsigned short)0;
    uint4* dst = (uint4*)(ot + ((size_t)((b << 9) + d) << 6));
#pragma unroll
    for (int i = 0; i < 8; ++i) dst[i] = bufv[i];
  }
}

// ---- main: per-(wb,b); GEMM1(scores+G)->softmax->logits->GEMM2(stream) ---
__global__ __launch_bounds__(128) void main_kernel(
    const unsigned short* __restrict__ wbf,
    const unsigned short* __restrict__ ubf,
    const unsigned short* __restrict__ obf,
    const unsigned short* __restrict__ ot,
    float* __restrict__ logits_ws,
    float* __restrict__ att_out,
    float* __restrict__ attV_out) {
  const int b = blockIdx.x, wb = blockIdx.y;
  const int tid = threadIdx.x;
  const int wave = tid >> 6;   // GEMM1 t-half: rows [wave*16, wave*16+16)
  const int lane = tid & 63;
  const int c = lane & 15;     // 16x16 col
  const int q = lane >> 4;     // quad

  __shared__ unsigned short att_s[TW][72];  // bf16 att, o-padded to 64
  __shared__ float att_f[TW][36];           // fp32 att staging for output

  {  // zero att_s (1152 dwords / 128 threads)
    unsigned int* p = (unsigned int*)&att_s[0][0];
#pragma unroll
    for (int i = 0; i < 9; ++i) p[tid + 128 * i] = 0u;
  }

  // -------- GEMM1: scores[t][o] = w.u  AND  G[t][o] = w.o ----------------
  const unsigned short* wbp = wbf + ((size_t)wb * TW + wave * 16) * DD;
  const unsigned short* ubp = ubf + (size_t)b * TO * DD;
  const unsigned short* obp = obf + (size_t)b * TO * DD;

  floatx4 accS[3], accG[3];
#pragma unroll
  for (int j = 0; j < 3; ++j) {
    accS[j] = (floatx4){0.f, 0.f, 0.f, 0.f};
    accG[j] = (floatx4){0.f, 0.f, 0.f, 0.f};
  }

  const int r2 = (c < 4) ? 32 + c : 35;  // clamp; cols 36..47 masked later
#pragma unroll 2
  for (int kk = 0; kk < 16; ++kk) {
    int k0 = kk * 32 + q * 8;
    short8 a0 = ld8(wbp + c * DD + k0);
    short8 u0 = ld8(ubp + c * DD + k0);
    short8 u1 = ld8(ubp + (16 + c) * DD + k0);
    short8 u2 = ld8(ubp + r2 * DD + k0);
    short8 o0 = ld8(obp + c * DD + k0);
    short8 o1 = ld8(obp + (16 + c) * DD + k0);
    short8 o2 = ld8(obp + r2 * DD + k0);
    accS[0] = __builtin_amdgcn_mfma_f32_16x16x32_bf16(a0, u0, accS[0], 0, 0, 0);
    accS[1] = __builtin_amdgcn_mfma_f32_16x16x32_bf16(a0, u1, accS[1], 0, 0, 0);
    accS[2] = __builtin_amdgcn_mfma_f32_16x16x32_bf16(a0, u2, accS[2], 0, 0, 0);
    accG[0] = __builtin_amdgcn_mfma_f32_16x16x32_bf16(a0, o0, accG[0], 0, 0, 0);
    accG[1] = __builtin_amdgcn_mfma_f32_16x16x32_bf16(a0, o1, accG[1], 0, 0, 0);
    accG[2] = __builtin_amdgcn_mfma_f32_16x16x32_bf16(a0, o2, accG[2], 0, 0, 0);
  }

  // -------- softmax over o + in-register logits (att . G) ----------------
  const float scale = 0.04419417382415922f;  // 1/sqrt(512)
  const bool v2 = (c < 4);
#pragma unroll
  for (int reg = 0; reg < 4; ++reg) {
    float s0 = accS[0][reg] * scale;
    float s1 = accS[1][reg] * scale;
    float s2 = accS[2][reg] * scale;
    float m = fmaxf(s0, s1);
    if (v2) m = fmaxf(m, s2);
#pragma unroll
    for (int off = 1; off < 16; off <<= 1) m = fmaxf(m, __shfl_xor(m, off));
    float e0 = __expf(s0 - m);
    float e1 = __expf(s1 - m);
    float e2 = v2 ? __expf(s2 - m) : 0.f;
    float sum = e0 + e1 + e2;
#pragma unroll
    for (int off = 1; off < 16; off <<= 1) sum += __shfl_xor(sum, off);
    float inv = 1.f / sum;
    float a0v = e0 * inv, a1v = e1 * inv, a2v = e2 * inv;
    int t = wave * 16 + q * 4 + reg;
    att_f[t][c] = a0v;
    att_f[t][16 + c] = a1v;
    if (v2) att_f[t][32 + c] = a2v;
    att_s[t][c] = f2bf(a0v);
    att_s[t][16 + c] = f2bf(a1v);
    if (v2) att_s[t][32 + c] = f2bf(a2v);
    // logits partial: att . G over this lane's 3 o-slots
    float lp = a0v * accG[0][reg] + a1v * accG[1][reg] + a2v * accG[2][reg];
#pragma unroll
    for (int off = 1; off < 16; off <<= 1) lp += __shfl_xor(lp, off);
    if (c == 0) logits_ws[(size_t)(wb * BB + b) * TW + t] = lp;
  }
  __syncthreads();

  // -------- stream att (full-line coalesced, from LDS) -------------------
  {
    float* attb = att_out + (size_t)(wb * BB + b) * TW * TO;
    const float* pf = &att_f[0][0];
#pragma unroll
    for (int i = 0; i < 9; ++i)
      __builtin_nontemporal_store(pf[tid + 128 * i], &attb[tid + 128 * i]);
  }

  // -------- GEMM2 (32x32x16): att_V_o[t][d], pure store stream -----------
  const int m32 = lane & 31, half = lane >> 5;
  short8 aF[4];
#pragma unroll
  for (int kc = 0; kc < 4; ++kc)
    aF[kc] = ld8(&att_s[m32][kc * 16 + half * 8]);

  const unsigned short* otp = ot + (size_t)b * DD * 64;
  float* avb = attV_out + (size_t)(wb * BB + b) * TW * DD;

#pragma unroll 2
  for (int i = 0; i < 8; ++i) {
    int d0 = (wave * 8 + i) * 32;
    const unsigned short* bp = otp + (size_t)(d0 + m32) * 64 + half * 8;
    short8 b0 = ld8(bp);
    short8 b1 = ld8(bp + 16);
    short8 b2 = ld8(bp + 32);
    short8 b3 = ld8(bp + 48);
    floatx16 acc = (floatx16){0.f, 0.f, 0.f, 0.f, 0.f, 0.f, 0.f, 0.f,
                              0.f, 0.f, 0.f, 0.f, 0.f, 0.f, 0.f, 0.f};
    acc = __builtin_amdgcn_mfma_f32_32x32x16_bf16(aF[0], b0, acc, 0, 0, 0);
    acc = __builtin_amdgcn_mfma_f32_32x32x16_bf16(aF[1], b1, acc, 0, 0, 0);
    acc = __builtin_amdgcn_mfma_f32_32x32x16_bf16(aF[2], b2, acc, 0, 0, 0);
    acc = __builtin_amdgcn_mfma_f32_32x32x16_bf16(aF[3], b3, acc, 0, 0, 0);
#pragma unroll
    for (int reg = 0; reg < 16; ++reg) {
      int row = (reg & 3) + 8 * (reg >> 2) + 4 * half;
      __builtin_nontemporal_store(acc[reg], &avb[row * DD + d0 + m32]);
    }
  }
}

// ---- loss: log_softmax over Bo + masked mean -----------------------------
__global__ __launch_bounds__(64) void loss_kernel(
    const float* __restrict__ logits, const int* __restrict__ mask,
    float* __restrict__ out) {
  int wb = blockIdx.x, lane = threadIdx.x;  // lane = b
  const float* lrow = logits + ((size_t)wb * BB + lane) * TW;
  float accv = 0.f, nnm = 0.f;
  for (int t = 0; t < TW; ++t) {
    float v = lrow[t];
    float m = v;
#pragma unroll
    for (int off = 1; off < 64; off <<= 1) m = fmaxf(m, __shfl_xor(m, off));
    float e = __expf(v - m);
    float s = e;
#pragma unroll
    for (int off = 1; off < 64; off <<= 1) s += __shfl_xor(s, off);
    float diag = __shfl(v, wb);  // logits[wb][wb][t]
    float lsm = diag - m - __logf(s);
    float keep = 1.f - (float)mask[wb * TW + t];
    accv += lsm * keep;
    nnm += keep;
  }
  if (lane == 0) atomicAdd(out, -(accv / (nnm + 1e-6f)) * (1.f / 64.f));
}

// ---- launch --------------------------------------------------------------
extern "C" void kernel_launch(void* const* d_in, const int* in_sizes, int n_in,
                              void* d_out, int out_size, void* d_ws, size_t ws_size,
                              hipStream_t stream) {
  const float* o_g = (const float*)d_in[0];   // (64,36,512) f32
  const float* u_g = (const float*)d_in[1];   // (64,36,512) f32
  const float* w_g = (const float*)d_in[2];   // (64,32,512) f32
  const int* mask  = (const int*)d_in[3];     // (64,32) i32

  float* out = (float*)d_out;
  float* att_out  = out + 1;
  float* attV_out = out + 1 + (size_t)BB * BB * TW * TO;

  char* ws = (char*)d_ws;
  unsigned short* wbf = (unsigned short*)(ws + 0);          // 2,097,152 B
  unsigned short* ubf = (unsigned short*)(ws + 2097152);    // 2,359,296 B
  unsigned short* obf = (unsigned short*)(ws + 4456448);    // 2,359,296 B
  unsigned short* ot  = (unsigned short*)(ws + 6815744);    // 4,194,304 B
  float* logits       = (float*)(ws + 11010048);            //   524,288 B

  hipMemsetAsync(d_out, 0, sizeof(float), stream);  // loss accumulator
  prep_kernel<<<1792, 256, 0, stream>>>(o_g, u_g, w_g, wbf, ubf, obf, ot);
  main_kernel<<<dim3(BB, BB), 128, 0, stream>>>(wbf, ubf, obf, ot, logits,
                                                att_out, attV_out);
  loss_kernel<<<BB, 64, 0, stream>>>(logits, mask, out);
}